// Round 1
// baseline (794.930 us; speedup 1.0000x reference)
//
#include <hip/hip_runtime.h>
#include <hip/hip_bf16.h>

#define NB 8192
#define ND 256
#define NKBP 63
#define NF 64
#define NE 64
#define NKP 16384   // D*F
#define NN 256      // output cols of projection (= D)
#define NDE 16384   // D*E

typedef __attribute__((ext_vector_type(8))) short short8_t;
typedef __attribute__((ext_vector_type(4))) float f32x4;

__device__ __forceinline__ unsigned short f2bf(float v) {
  unsigned int b = __float_as_uint(v);
  b = (b + 0x7FFFu + ((b >> 16) & 1u)) >> 16;
  return (unsigned short)b;
}

// ---------------- K1: breakpoints = bmin + cumsum(softplus(draw)) ----------------
__global__ void k_bp(const float* __restrict__ bmin, const float* __restrict__ draw,
                     float* __restrict__ obp) {
  const int d = blockIdx.x * blockDim.x + threadIdx.x;
  if (d >= ND) return;
  float a = bmin[d];
  for (int j = 0; j < NKBP; ++j) {
    float r = draw[d * NKBP + j];
    a += fmaxf(r, 0.f) + log1pf(expf(-fabsf(r)));
    obp[d * NKBP + j] = a;
  }
}

// ---------------- K2a: xT[d][b] = bf16(x[b][d]) ----------------
__global__ void k_xt(const float* __restrict__ x, __hip_bfloat16* __restrict__ xT) {
  __shared__ float tile[64 * 65];
  const int b0 = blockIdx.x * 64;
  const int d0 = blockIdx.y * 64;
  const int t = threadIdx.x;
  for (int i = t; i < 4096; i += 256) {
    int r = i >> 6, c = i & 63;
    tile[r * 65 + c] = x[(size_t)(b0 + r) * ND + d0 + c];
  }
  __syncthreads();
  for (int i = t; i < 4096; i += 256) {
    int r = i & 63, c = i >> 6;
    xT[(size_t)(d0 + c) * NB + b0 + r] = __float2bfloat16(tile[r * 65 + c]);
  }
}

// ---------------- K2c: cbias[n] = sum_i bb_flat[i] * pw[n][i] ----------------
__global__ void k_cb(const float* __restrict__ bb, const float* __restrict__ pw,
                     float* __restrict__ c) {
  const int n = blockIdx.x;
  const int t = threadIdx.x;
  const float* pwr = pw + (size_t)n * NDE;
  float acc = 0.f;
  for (int i = t; i < NDE; i += 256) acc += bb[i] * pwr[i];
  #pragma unroll
  for (int off = 32; off > 0; off >>= 1) acc += __shfl_down(acc, off, 64);
  __shared__ float red[4];
  if ((t & 63) == 0) red[t >> 6] = acc;
  __syncthreads();
  if (t == 0) c[n] = red[0] + red[1] + red[2] + red[3];
}

// ---------------- K2b: W2T[n][d*64+f] = bf16( sum_e bw[d][f][e] * pw[n][d*64+e] ) ----------------
__global__ void k_w2(const float* __restrict__ bw, const float* __restrict__ pw,
                     __hip_bfloat16* __restrict__ w2t) {
  const int d = blockIdx.x;
  const int t = threadIdx.x;
  __shared__ float bwS[NF * 68];
  const float* bwd = bw + (size_t)d * (NF * NE);
  for (int i = t; i < NF * NE; i += 256)
    bwS[(i >> 6) * 68 + (i & 63)] = bwd[i];
  __syncthreads();
  const int f = t & 63, w = t >> 6;
  for (int j = 0; j < 64; ++j) {
    const int n = w * 64 + j;
    const float* pwr = pw + (size_t)n * NDE + d * NE;
    float acc = 0.f;
    #pragma unroll
    for (int e = 0; e < NE; e += 4) {
      f32x4 p = *(const f32x4*)(pwr + e);
      f32x4 bv = *(const f32x4*)(bwS + f * 68 + e);
      acc += bv[0] * p[0] + bv[1] * p[1] + bv[2] * p[2] + bv[3] * p[3];
    }
    w2t[(size_t)n * NKP + d * NF + f] = __float2bfloat16(acc);
  }
}

// ---------------- K3: projection GEMM, basis recomputed per K-step ----------------
// x_emb[b][n] = x[b][n] + 0.1*( sum_{d,f} basis[b,d,f]*W2T[n][d*64+f] + cbias[n] + pb[n] )
// Tile 64x64, BK=64 (one d per step). 4 waves, wave grid 2x2, wave tile 32x32.
__global__ __launch_bounds__(256, 2) void k_proj(
    const __hip_bfloat16* __restrict__ xT, const __hip_bfloat16* __restrict__ w2t,
    const float* __restrict__ bp, const float* __restrict__ x,
    const float* __restrict__ pb, const float* __restrict__ cb,
    float* __restrict__ xe) {
  __shared__ char As[64 * 128];      // [m=64][k=64] bf16, XOR-swizzled rows (128 B)
  __shared__ float bpAll[ND * NF];   // 64 KB: bpAll[d*64+f] = breakpoints[d][f-1] (f>=1)
  const int t = threadIdx.x;
  const int l = t & 63;
  const int w = t >> 6;
  const int wm = w >> 1, wn = w & 1;
  const int bM = blockIdx.x * 64;
  const int bN = blockIdx.y * 64;
  const int lr = l & 15, lg = l >> 4;
  const int f0 = w * 16;
  const unsigned int wsw = ((unsigned)(l & 7)) << 4;

  for (int i = t; i < ND * NF; i += 256) {
    int dd = i >> 6, f = i & 63;
    bpAll[i] = (f >= 1) ? bp[dd * NKBP + f - 1] : 0.0f;
  }
  __syncthreads();

  f32x4 acc[2][2];
  #pragma unroll
  for (int mi = 0; mi < 2; ++mi)
    #pragma unroll
    for (int ni = 0; ni < 2; ++ni)
      acc[mi][ni] = (f32x4){0.f, 0.f, 0.f, 0.f};

  const unsigned short* w2u = (const unsigned short*)w2t;

  for (int d = 0; d < ND; ++d) {
    // stage A: basis tile [64 b][64 f] in bf16 (lane l owns row b=l, wave owns 16 f cols)
    float xv = __bfloat162float(xT[(size_t)d * NB + bM + l]);
    short8_t v0, v1;
    #pragma unroll
    for (int j = 0; j < 8; ++j) {
      int f = f0 + j;
      float bv = (f == 0) ? xv : fmaxf(xv - bpAll[d * NF + f], 0.0f);
      v0[j] = (short)f2bf(bv);
    }
    #pragma unroll
    for (int j = 0; j < 8; ++j) {
      int f = f0 + 8 + j;
      float bv = fmaxf(xv - bpAll[d * NF + f], 0.0f);
      v1[j] = (short)f2bf(bv);
    }
    unsigned int base = (unsigned)(l * 128 + f0 * 2);
    *(short8_t*)(As + (base ^ wsw)) = v0;
    *(short8_t*)(As + ((base + 16) ^ wsw)) = v1;
    __syncthreads();

    #pragma unroll
    for (int kf = 0; kf < 2; ++kf) {
      short8_t afr[2], bfr[2];
      #pragma unroll
      for (int ni = 0; ni < 2; ++ni) {
        int n = bN + wn * 32 + ni * 16 + lr;
        bfr[ni] = *(const short8_t*)(w2u + ((size_t)n * NKP + d * 64 + kf * 32 + lg * 8));
      }
      #pragma unroll
      for (int mi = 0; mi < 2; ++mi) {
        int m = wm * 32 + mi * 16 + lr;
        unsigned int off = (unsigned)(m * 128 + (kf * 32 + lg * 8) * 2);
        afr[mi] = *(const short8_t*)(As + (off ^ (((unsigned)(m & 7)) << 4)));
      }
      #pragma unroll
      for (int mi = 0; mi < 2; ++mi)
        #pragma unroll
        for (int ni = 0; ni < 2; ++ni)
          acc[mi][ni] = __builtin_amdgcn_mfma_f32_16x16x32_bf16(afr[mi], bfr[ni], acc[mi][ni], 0, 0, 0);
    }
    __syncthreads();
  }

  #pragma unroll
  for (int mi = 0; mi < 2; ++mi) {
    #pragma unroll
    for (int ni = 0; ni < 2; ++ni) {
      int col = bN + wn * 32 + ni * 16 + lr;
      float cbv = cb[col] + pb[col];
      #pragma unroll
      for (int r = 0; r < 4; ++r) {
        int row = bM + wm * 32 + mi * 16 + lg * 4 + r;
        xe[(size_t)row * NN + col] = x[(size_t)row * NN + col] + 0.1f * (acc[mi][ni][r] + cbv);
      }
    }
  }
}

// ---------------- K4: embeddings in exact fp32 (overwrites scratch region) ----------------
// Tile: 128 b x 64 e per block (one d). 256 threads, 8b x 4e register micro-tile.
__global__ __launch_bounds__(256) void k_emb(
    const float* __restrict__ x, const float* __restrict__ bw,
    const float* __restrict__ bb, const float* __restrict__ bp,
    float* __restrict__ oe) {
  const int d = blockIdx.y;
  const int b0 = blockIdx.x * 128;
  const int t = threadIdx.x;
  __shared__ float bwS[NF * 68];
  __shared__ float baS[NF * 132];
  __shared__ float xS[128];
  __shared__ float bpS[64];

  const float* bwd = bw + (size_t)d * (NF * NE);
  for (int i = t; i < 1024; i += 256) {
    int f = i >> 4, e4 = (i & 15) << 2;
    *(f32x4*)(bwS + f * 68 + e4) = *(const f32x4*)(bwd + f * 64 + e4);
  }
  if (t < 128) xS[t] = x[(size_t)(b0 + t) * ND + d];
  if (t < NKBP) bpS[t + 1] = bp[d * NKBP + t];
  if (t == 255) bpS[0] = 0.f;
  __syncthreads();
  for (int i = t; i < NF * 128; i += 256) {
    int f = i >> 7, b = i & 127;
    float xv = xS[b];
    baS[f * 132 + b] = (f == 0) ? xv : fmaxf(xv - bpS[f], 0.0f);
  }
  __syncthreads();

  const int te = (t >> 4) << 2;   // e base: 0..60
  const int tb = (t & 15) << 3;   // b base: 0..120
  float acc[8][4];
  #pragma unroll
  for (int i = 0; i < 8; ++i)
    #pragma unroll
    for (int j = 0; j < 4; ++j) acc[i][j] = 0.f;

  for (int f = 0; f < NF; ++f) {
    f32x4 wv = *(const f32x4*)(bwS + f * 68 + te);
    f32x4 bva = *(const f32x4*)(baS + f * 132 + tb);
    f32x4 bvb = *(const f32x4*)(baS + f * 132 + tb + 4);
    #pragma unroll
    for (int i = 0; i < 4; ++i) {
      float bv = bva[i];
      acc[i][0] += bv * wv[0]; acc[i][1] += bv * wv[1];
      acc[i][2] += bv * wv[2]; acc[i][3] += bv * wv[3];
    }
    #pragma unroll
    for (int i = 0; i < 4; ++i) {
      float bv = bvb[i];
      acc[4 + i][0] += bv * wv[0]; acc[4 + i][1] += bv * wv[1];
      acc[4 + i][2] += bv * wv[2]; acc[4 + i][3] += bv * wv[3];
    }
  }
  const float* bbd = bb + (size_t)d * NE;
  f32x4 bias = *(const f32x4*)(bbd + te);
  #pragma unroll
  for (int i = 0; i < 8; ++i) {
    f32x4 o;
    o[0] = acc[i][0] + bias[0]; o[1] = acc[i][1] + bias[1];
    o[2] = acc[i][2] + bias[2]; o[3] = acc[i][3] + bias[3];
    *(f32x4*)(oe + (size_t)(b0 + tb + i) * NDE + d * 64 + te) = o;
  }
}

extern "C" void kernel_launch(void* const* d_in, const int* in_sizes, int n_in,
                              void* d_out, int out_size, void* d_ws, size_t ws_size,
                              hipStream_t stream) {
  const float* x    = (const float*)d_in[0];
  const float* bw   = (const float*)d_in[1];
  const float* bb   = (const float*)d_in[2];
  const float* pw   = (const float*)d_in[3];
  const float* pb   = (const float*)d_in[4];
  const float* bmin = (const float*)d_in[5];
  const float* draw = (const float*)d_in[6];

  float* out   = (float*)d_out;
  float* out_x  = out;                                   // [8192*256]
  float* out_e  = out + (size_t)NB * ND;                 // [8192*256*64]
  float* out_bp = out_e + (size_t)NB * NDE;              // [256*63]

  // Scratch at head of embeddings region (overwritten last by k_emb):
  __hip_bfloat16* w2t = (__hip_bfloat16*)out_e;                  // 256*16384 bf16 = 8.39 MB
  __hip_bfloat16* xT  = (__hip_bfloat16*)(out_e + 2097152);      // 256*8192 bf16  = 4.19 MB
  float* cbuf = out_e + 2097152 + 1048576;                       // 256 f32

  k_bp  <<<dim3(1),       dim3(256), 0, stream>>>(bmin, draw, out_bp);
  k_xt  <<<dim3(128, 4),  dim3(256), 0, stream>>>(x, xT);
  k_cb  <<<dim3(256),     dim3(256), 0, stream>>>(bb, pw, cbuf);
  k_w2  <<<dim3(256),     dim3(256), 0, stream>>>(bw, pw, w2t);
  k_proj<<<dim3(128, 4),  dim3(256), 0, stream>>>(xT, w2t, out_bp, x, pb, cbuf, out_x);
  k_emb <<<dim3(64, 256), dim3(256), 0, stream>>>(x, bw, bb, out_bp, out_e);
}

// Round 3
// 410.220 us; speedup vs baseline: 1.9378x; 1.9378x over previous
//
#include <hip/hip_runtime.h>
#include <hip/hip_bf16.h>

#define NB 8192
#define ND 256
#define NKBP 63
#define NF 64
#define NE 64
#define NKP 16384   // D*F
#define NDE 16384   // D*E

typedef __attribute__((ext_vector_type(8))) short short8_t;
typedef __attribute__((ext_vector_type(4))) float f32x4;

__device__ __forceinline__ unsigned short f2bf(float v) {
  unsigned int b = __float_as_uint(v);
  b = (b + 0x7FFFu + ((b >> 16) & 1u)) >> 16;
  return (unsigned short)b;
}

// ---------------- K1: breakpoints = bmin + cumsum(softplus(draw)) ----------------
__global__ void k_bp(const float* __restrict__ bmin, const float* __restrict__ draw,
                     float* __restrict__ obp) {
  const int d = blockIdx.x * blockDim.x + threadIdx.x;
  if (d >= ND) return;
  float a = bmin[d];
  for (int j = 0; j < NKBP; ++j) {
    float r = draw[d * NKBP + j];
    a += fmaxf(r, 0.f) + log1pf(expf(-fabsf(r)));
    obp[d * NKBP + j] = a;
  }
}

// ---------------- K2c: cbias[n] = sum_i bb_flat[i] * pw[n][i] ----------------
__global__ void k_cb(const float* __restrict__ bb, const float* __restrict__ pw,
                     float* __restrict__ c) {
  const int n = blockIdx.x;
  const int t = threadIdx.x;
  const float* pwr = pw + (size_t)n * NDE;
  float acc = 0.f;
  for (int i = t; i < NDE; i += 256) acc += bb[i] * pwr[i];
  #pragma unroll
  for (int off = 32; off > 0; off >>= 1) acc += __shfl_down(acc, off, 64);
  __shared__ float red[4];
  if ((t & 63) == 0) red[t >> 6] = acc;
  __syncthreads();
  if (t == 0) c[n] = red[0] + red[1] + red[2] + red[3];
}

// ---------------- K2b: W2T[n][d*64+f] = bf16( sum_e bw[d][f][e] * pw[n][d*64+e] ) ----------------
__global__ void k_w2(const float* __restrict__ bw, const float* __restrict__ pw,
                     __hip_bfloat16* __restrict__ w2t) {
  const int d = blockIdx.x;
  const int t = threadIdx.x;
  __shared__ float bwS[NF * 68];
  const float* bwd = bw + (size_t)d * (NF * NE);
  for (int i = t; i < NF * NE; i += 256)
    bwS[(i >> 6) * 68 + (i & 63)] = bwd[i];
  __syncthreads();
  const int f = t & 63, w = t >> 6;
  for (int j = 0; j < 64; ++j) {
    const int n = w * 64 + j;
    const float* pwr = pw + (size_t)n * NDE + d * NE;
    float acc = 0.f;
    #pragma unroll
    for (int e = 0; e < NE; e += 4) {
      f32x4 p = *(const f32x4*)(pwr + e);
      f32x4 bv = *(const f32x4*)(bwS + f * 68 + e);
      acc += bv[0] * p[0] + bv[1] * p[1] + bv[2] * p[2] + bv[3] * p[3];
    }
    w2t[(size_t)n * NKP + d * NF + f] = __float2bfloat16(acc);
  }
}

// ---------------- K3: projection GEMM partials. Split-K x4, no barriers in K-loop.
// wave-tile 64x64 (mi=4, ni=4), A (basis) computed in registers, B from global w2t.
__global__ __launch_bounds__(256, 2) void k_proj(
    const unsigned short* __restrict__ w2u, const float* __restrict__ bp,
    const float* __restrict__ x, float* __restrict__ pbuf) {
  const int t = threadIdx.x;
  const int l = t & 63, w = t >> 6;
  const int lr = l & 15, lg = l >> 4;
  const int bM = blockIdx.x * 256;
  const int bN = blockIdx.y * 64;
  const int d0 = blockIdx.z * 64;
  __shared__ float thrS[64 * 64];   // thrS[dl*64+f] = (f==0)?0:bp[d0+dl][f-1]

  for (int i = t; i < 4096; i += 256) {
    const int dl = i >> 6, f = i & 63;
    thrS[i] = (f >= 1) ? bp[(size_t)(d0 + dl) * NKBP + f - 1] : 0.0f;
  }
  __syncthreads();

  f32x4 acc[4][4];
  #pragma unroll
  for (int mi = 0; mi < 4; ++mi)
    #pragma unroll
    for (int ni = 0; ni < 4; ++ni) acc[mi][ni] = (f32x4){0.f, 0.f, 0.f, 0.f};

  const bool lg0 = (lg == 0);
  const unsigned short* bptr[4];
  #pragma unroll
  for (int ni = 0; ni < 4; ++ni)
    bptr[ni] = w2u + (size_t)(bN + ni * 16 + lr) * NKP + (size_t)d0 * 64 + lg * 8;
  const float* xrow[4];
  #pragma unroll
  for (int mi = 0; mi < 4; ++mi)
    xrow[mi] = x + (size_t)(bM + w * 64 + mi * 16 + lr) * ND + d0;

  for (int c = 0; c < 8; ++c) {
    f32x4 xqa[4], xqb[4];
    #pragma unroll
    for (int mi = 0; mi < 4; ++mi) {
      xqa[mi] = *(const f32x4*)(xrow[mi] + c * 8);
      xqb[mi] = *(const f32x4*)(xrow[mi] + c * 8 + 4);
    }
    #pragma unroll
    for (int dd = 0; dd < 8; ++dd) {
      const int dl = c * 8 + dd;
      short8_t bfr[2][4];
      #pragma unroll
      for (int kf = 0; kf < 2; ++kf)
        #pragma unroll
        for (int ni = 0; ni < 4; ++ni)
          bfr[kf][ni] = *(const short8_t*)(bptr[ni] + dl * 64 + kf * 32);
      const float* tp = thrS + dl * 64 + lg * 8;
      f32x4 ta = *(const f32x4*)(tp);
      f32x4 tb = *(const f32x4*)(tp + 4);
      f32x4 tc = *(const f32x4*)(tp + 32);
      f32x4 td = *(const f32x4*)(tp + 36);
      short8_t afr[4][2];
      #pragma unroll
      for (int mi = 0; mi < 4; ++mi) {
        const float xv = (dd < 4) ? xqa[mi][dd & 3] : xqb[mi][dd & 3];
        short8_t A0, A1;
        A0[0] = (short)f2bf(lg0 ? xv : fmaxf(xv - ta[0], 0.f));
        A0[1] = (short)f2bf(fmaxf(xv - ta[1], 0.f));
        A0[2] = (short)f2bf(fmaxf(xv - ta[2], 0.f));
        A0[3] = (short)f2bf(fmaxf(xv - ta[3], 0.f));
        A0[4] = (short)f2bf(fmaxf(xv - tb[0], 0.f));
        A0[5] = (short)f2bf(fmaxf(xv - tb[1], 0.f));
        A0[6] = (short)f2bf(fmaxf(xv - tb[2], 0.f));
        A0[7] = (short)f2bf(fmaxf(xv - tb[3], 0.f));
        A1[0] = (short)f2bf(fmaxf(xv - tc[0], 0.f));
        A1[1] = (short)f2bf(fmaxf(xv - tc[1], 0.f));
        A1[2] = (short)f2bf(fmaxf(xv - tc[2], 0.f));
        A1[3] = (short)f2bf(fmaxf(xv - tc[3], 0.f));
        A1[4] = (short)f2bf(fmaxf(xv - td[0], 0.f));
        A1[5] = (short)f2bf(fmaxf(xv - td[1], 0.f));
        A1[6] = (short)f2bf(fmaxf(xv - td[2], 0.f));
        A1[7] = (short)f2bf(fmaxf(xv - td[3], 0.f));
        afr[mi][0] = A0;
        afr[mi][1] = A1;
      }
      #pragma unroll
      for (int kf = 0; kf < 2; ++kf)
        #pragma unroll
        for (int mi = 0; mi < 4; ++mi)
          #pragma unroll
          for (int ni = 0; ni < 4; ++ni)
            acc[mi][ni] = __builtin_amdgcn_mfma_f32_16x16x32_bf16(afr[mi][kf], bfr[kf][ni], acc[mi][ni], 0, 0, 0);
    }
  }

  float* pp = pbuf + (size_t)blockIdx.z * ((size_t)NB * ND);
  #pragma unroll
  for (int mi = 0; mi < 4; ++mi)
    #pragma unroll
    for (int ni = 0; ni < 4; ++ni) {
      const int col = bN + ni * 16 + lr;
      const int rowb = bM + w * 64 + mi * 16 + lg * 4;
      #pragma unroll
      for (int r = 0; r < 4; ++r)
        pp[(size_t)(rowb + r) * ND + col] = acc[mi][ni][r];
    }
}

// ---------------- K4: combine partials -> x_emb ----------------
__global__ void k_comb(const float* __restrict__ x, const float* __restrict__ pbuf,
                       const float* __restrict__ cbuf, const float* __restrict__ pb,
                       float* __restrict__ xe) {
  const size_t i = ((size_t)blockIdx.x * 256 + threadIdx.x) * 4;
  const int n = (int)(i & 255);
  f32x4 s = *(const f32x4*)(pbuf + i);
  s += *(const f32x4*)(pbuf + (size_t)1 * 2097152 + i);
  s += *(const f32x4*)(pbuf + (size_t)2 * 2097152 + i);
  s += *(const f32x4*)(pbuf + (size_t)3 * 2097152 + i);
  f32x4 cv = *(const f32x4*)(cbuf + n);
  f32x4 pv = *(const f32x4*)(pb + n);
  f32x4 xv = *(const f32x4*)(x + i);
  *(f32x4*)(xe + i) = xv + 0.1f * (s + cv + pv);
}

// ---------------- K5: embeddings via bf16 MFMA (write-BW-bound) ----------------
__global__ __launch_bounds__(256, 2) void k_emb(
    const float* __restrict__ x, const float* __restrict__ bw,
    const float* __restrict__ bb, const float* __restrict__ bp,
    float* __restrict__ oe) {
  const int d = blockIdx.y;
  const int b0 = blockIdx.x * 256;
  const int t = threadIdx.x;
  const int l = t & 63, w = t >> 6;
  const int lr = l & 15, lg = l >> 4;
  __shared__ char btS[64 * 128];   // [e][f] bf16 swizzled (transposed bw[d])
  __shared__ float thrF[64];
  __shared__ float bbS[64];
  if (t < 64) thrF[t] = (t >= 1) ? bp[(size_t)d * NKBP + t - 1] : 0.0f;
  else if (t < 128) bbS[t - 64] = bb[(size_t)d * 64 + (t - 64)];
  {
    const float* bwd = bw + (size_t)d * 4096;
    const int f = t >> 2, e0 = (t & 3) * 16;
    #pragma unroll
    for (int q = 0; q < 4; ++q) {
      f32x4 v = *(const f32x4*)(bwd + f * 64 + e0 + q * 4);
      #pragma unroll
      for (int r = 0; r < 4; ++r) {
        const int e = e0 + q * 4 + r;
        unsigned off = ((unsigned)(e * 128 + f * 2)) ^ (((unsigned)(e & 7)) << 4);
        *(unsigned short*)(btS + off) = f2bf(v[r]);
      }
    }
  }
  __syncthreads();

  f32x4 ta = *(const f32x4*)(thrF + lg * 8);
  f32x4 tb = *(const f32x4*)(thrF + lg * 8 + 4);
  f32x4 tc = *(const f32x4*)(thrF + 32 + lg * 8);
  f32x4 td = *(const f32x4*)(thrF + 36 + lg * 8);
  const bool lg0 = (lg == 0);

  short8_t afr[4][2];
  #pragma unroll
  for (int mi = 0; mi < 4; ++mi) {
    const float xv = x[(size_t)(b0 + w * 64 + mi * 16 + lr) * ND + d];
    short8_t A0, A1;
    A0[0] = (short)f2bf(lg0 ? xv : fmaxf(xv - ta[0], 0.f));
    A0[1] = (short)f2bf(fmaxf(xv - ta[1], 0.f));
    A0[2] = (short)f2bf(fmaxf(xv - ta[2], 0.f));
    A0[3] = (short)f2bf(fmaxf(xv - ta[3], 0.f));
    A0[4] = (short)f2bf(fmaxf(xv - tb[0], 0.f));
    A0[5] = (short)f2bf(fmaxf(xv - tb[1], 0.f));
    A0[6] = (short)f2bf(fmaxf(xv - tb[2], 0.f));
    A0[7] = (short)f2bf(fmaxf(xv - tb[3], 0.f));
    A1[0] = (short)f2bf(fmaxf(xv - tc[0], 0.f));
    A1[1] = (short)f2bf(fmaxf(xv - tc[1], 0.f));
    A1[2] = (short)f2bf(fmaxf(xv - tc[2], 0.f));
    A1[3] = (short)f2bf(fmaxf(xv - tc[3], 0.f));
    A1[4] = (short)f2bf(fmaxf(xv - td[0], 0.f));
    A1[5] = (short)f2bf(fmaxf(xv - td[1], 0.f));
    A1[6] = (short)f2bf(fmaxf(xv - td[2], 0.f));
    A1[7] = (short)f2bf(fmaxf(xv - td[3], 0.f));
    afr[mi][0] = A0;
    afr[mi][1] = A1;
  }
  short8_t bfr[4][2];
  #pragma unroll
  for (int ni = 0; ni < 4; ++ni) {
    const int e = ni * 16 + lr;
    #pragma unroll
    for (int kf = 0; kf < 2; ++kf) {
      unsigned off = ((unsigned)(e * 128 + (kf * 32 + lg * 8) * 2)) ^ (((unsigned)(e & 7)) << 4);
      bfr[ni][kf] = *(const short8_t*)(btS + off);
    }
  }
  f32x4 acc[4][4];
  #pragma unroll
  for (int mi = 0; mi < 4; ++mi)
    #pragma unroll
    for (int ni = 0; ni < 4; ++ni) acc[mi][ni] = (f32x4){0.f, 0.f, 0.f, 0.f};
  #pragma unroll
  for (int kf = 0; kf < 2; ++kf)
    #pragma unroll
    for (int mi = 0; mi < 4; ++mi)
      #pragma unroll
      for (int ni = 0; ni < 4; ++ni)
        acc[mi][ni] = __builtin_amdgcn_mfma_f32_16x16x32_bf16(afr[mi][kf], bfr[ni][kf], acc[mi][ni], 0, 0, 0);

  #pragma unroll
  for (int ni = 0; ni < 4; ++ni) {
    const float bbv = bbS[ni * 16 + lr];
    const int col = d * 64 + ni * 16 + lr;
    #pragma unroll
    for (int mi = 0; mi < 4; ++mi) {
      const int rowb = b0 + w * 64 + mi * 16 + lg * 4;
      #pragma unroll
      for (int r = 0; r < 4; ++r)
        oe[(size_t)(rowb + r) * NDE + col] = acc[mi][ni][r] + bbv;
    }
  }
}

extern "C" void kernel_launch(void* const* d_in, const int* in_sizes, int n_in,
                              void* d_out, int out_size, void* d_ws, size_t ws_size,
                              hipStream_t stream) {
  const float* x    = (const float*)d_in[0];
  const float* bw   = (const float*)d_in[1];
  const float* bb   = (const float*)d_in[2];
  const float* pw   = (const float*)d_in[3];
  const float* pb   = (const float*)d_in[4];
  const float* bmin = (const float*)d_in[5];
  const float* draw = (const float*)d_in[6];

  float* out    = (float*)d_out;
  float* out_x  = out;                          // [8192*256]
  float* out_e  = out + (size_t)NB * ND;        // [8192*256*64]
  float* out_bp = out_e + (size_t)NB * NDE;     // [256*63]

  // Scratch: w2t fills out_x region EXACTLY (2M f32 = 4.2M bf16); overwritten by k_comb after k_proj.
  __hip_bfloat16* w2t = (__hip_bfloat16*)out_x;
  // cbuf + split-K partials at head of out_e; consumed by k_comb, then overwritten by k_emb.
  float* cbuf = out_e;                          // 256 f32
  float* pbuf = out_e + 65536;                  // 4 * 2097152 f32 = 33.5 MB

  k_bp  <<<dim3(1),          dim3(256), 0, stream>>>(bmin, draw, out_bp);
  k_w2  <<<dim3(256),        dim3(256), 0, stream>>>(bw, pw, w2t);
  k_cb  <<<dim3(256),        dim3(256), 0, stream>>>(bb, pw, cbuf);
  k_proj<<<dim3(32, 4, 4),   dim3(256), 0, stream>>>((const unsigned short*)w2t, out_bp, x, pbuf);
  k_comb<<<dim3(2048),       dim3(256), 0, stream>>>(x, pbuf, cbuf, pb, out_x);
  k_emb <<<dim3(32, 256),    dim3(256), 0, stream>>>(x, bw, bb, out_bp, out_e);
}

// Round 4
// 317.495 us; speedup vs baseline: 2.5038x; 1.2921x over previous
//
#include <hip/hip_runtime.h>
#include <hip/hip_bf16.h>

#define NB 8192
#define ND 256
#define NKBP 63
#define NF 64
#define NE 64
#define NKP 16384   // D*F
#define NDE 16384   // D*E

typedef __attribute__((ext_vector_type(8))) short short8_t;
typedef __attribute__((ext_vector_type(4))) short short4_t;
typedef __attribute__((ext_vector_type(4))) float f32x4;

__device__ __forceinline__ unsigned short bfbits(float v) {
  union { __hip_bfloat16 b; unsigned short u; } cv;
  cv.b = __float2bfloat16(v);
  return cv.u;
}
__device__ __forceinline__ float bf2f(unsigned short s) {
  return __uint_as_float(((unsigned)s) << 16);
}

// ---------------- K1: breakpoints = bmin + cumsum(softplus(draw)) ----------------
__global__ void k_bp(const float* __restrict__ bmin, const float* __restrict__ draw,
                     float* __restrict__ obp) {
  const int d = blockIdx.x * blockDim.x + threadIdx.x;
  if (d >= ND) return;
  float a = bmin[d];
  for (int j = 0; j < NKBP; ++j) {
    float r = draw[d * NKBP + j];
    a += fmaxf(r, 0.f) + log1pf(expf(-fabsf(r)));
    obp[d * NKBP + j] = a;
  }
}

// ---------------- K2: W2T[n][d*64+f] = bf16( sum_e bw[d][f][e] * pw[n][d*64+e] )  (MFMA)
//                 + cb_part[d][n] = sum_e bb[d][e] * pw[n][d*64+e]
__global__ __launch_bounds__(256, 2) void k_w2(
    const float* __restrict__ bw, const float* __restrict__ pw,
    const float* __restrict__ bb, unsigned short* __restrict__ w2t,
    float* __restrict__ cb_part) {
  const int d = blockIdx.x;
  const int t = threadIdx.x;
  const int l = t & 63, w = t >> 6;
  const int lr = l & 15, lg = l >> 4;
  __shared__ unsigned short pwS[256 * 72];  // [n][e] bf16, rows padded to 72 (144 B)
  __shared__ unsigned short bwS[64 * 72];   // [f][e] bf16
  __shared__ float bbS[64];

  {  // stage pw slice [256 n][64 e] -> bf16 LDS, coalesced (16 lanes per row)
    const int rr = t >> 4, e0 = (t & 15) * 4;
    #pragma unroll
    for (int it = 0; it < 16; ++it) {
      const int n = it * 16 + rr;
      f32x4 v = *(const f32x4*)(pw + (size_t)n * NDE + d * 64 + e0);
      short4_t s;
      s[0] = (short)bfbits(v[0]); s[1] = (short)bfbits(v[1]);
      s[2] = (short)bfbits(v[2]); s[3] = (short)bfbits(v[3]);
      *(short4_t*)(pwS + n * 72 + e0) = s;
    }
    #pragma unroll
    for (int it = 0; it < 4; ++it) {
      const int f = it * 16 + rr;
      f32x4 v = *(const f32x4*)(bw + (size_t)d * 4096 + f * 64 + e0);
      short4_t s;
      s[0] = (short)bfbits(v[0]); s[1] = (short)bfbits(v[1]);
      s[2] = (short)bfbits(v[2]); s[3] = (short)bfbits(v[3]);
      *(short4_t*)(bwS + f * 72 + e0) = s;
    }
    if (t < 64) bbS[t] = bb[(size_t)d * 64 + t];
  }
  __syncthreads();

  f32x4 acc[4][4];
  #pragma unroll
  for (int mi = 0; mi < 4; ++mi)
    #pragma unroll
    for (int ni = 0; ni < 4; ++ni) acc[mi][ni] = (f32x4){0.f, 0.f, 0.f, 0.f};

  short8_t afr[4][2], bfr[4][2];
  #pragma unroll
  for (int kf = 0; kf < 2; ++kf) {
    #pragma unroll
    for (int mi = 0; mi < 4; ++mi) {
      const int n = w * 64 + mi * 16 + lr;
      afr[mi][kf] = *(const short8_t*)(pwS + n * 72 + kf * 32 + lg * 8);
    }
    #pragma unroll
    for (int ni = 0; ni < 4; ++ni) {
      const int f = ni * 16 + lr;
      bfr[ni][kf] = *(const short8_t*)(bwS + f * 72 + kf * 32 + lg * 8);
    }
  }
  #pragma unroll
  for (int kf = 0; kf < 2; ++kf)
    #pragma unroll
    for (int mi = 0; mi < 4; ++mi)
      #pragma unroll
      for (int ni = 0; ni < 4; ++ni)
        acc[mi][ni] = __builtin_amdgcn_mfma_f32_16x16x32_bf16(afr[mi][kf], bfr[ni][kf], acc[mi][ni], 0, 0, 0);

  #pragma unroll
  for (int mi = 0; mi < 4; ++mi)
    #pragma unroll
    for (int ni = 0; ni < 4; ++ni) {
      const int f = ni * 16 + lr;
      const int nb = w * 64 + mi * 16 + lg * 4;
      #pragma unroll
      for (int r = 0; r < 4; ++r)
        w2t[(size_t)(nb + r) * NKP + d * 64 + f] = bfbits(acc[mi][ni][r]);
    }

  // cbias partial for this d: thread t owns n = t
  {
    float cacc = 0.f;
    #pragma unroll 8
    for (int e = 0; e < 64; ++e) cacc += bf2f(pwS[t * 72 + e]) * bbS[e];
    cb_part[(size_t)d * 256 + t] = cacc;
  }
}

// ---------------- K2r: cbias[n] = sum_d cb_part[d][n] ----------------
__global__ void k_cbr(const float* __restrict__ cb_part, float* __restrict__ c) {
  const int t = threadIdx.x;
  float acc = 0.f;
  for (int d = 0; d < ND; ++d) acc += cb_part[(size_t)d * 256 + t];
  c[t] = acc;
}

// ---------------- K3: projection GEMM partials. Split-K x4, no barriers in K-loop.
// wave-tile 64x64 (mi=4, ni=4), A (basis) computed in registers, B from global w2t.
__global__ __launch_bounds__(256, 2) void k_proj(
    const unsigned short* __restrict__ w2u, const float* __restrict__ bp,
    const float* __restrict__ x, float* __restrict__ pbuf) {
  const int t = threadIdx.x;
  const int l = t & 63, w = t >> 6;
  const int lr = l & 15, lg = l >> 4;
  const int bM = blockIdx.x * 256;
  const int bN = blockIdx.y * 64;
  const int d0 = blockIdx.z * 64;
  __shared__ float thrS[64 * 64];   // thrS[dl*64+f] = (f==0)?0:bp[d0+dl][f-1]

  for (int i = t; i < 4096; i += 256) {
    const int dl = i >> 6, f = i & 63;
    thrS[i] = (f >= 1) ? bp[(size_t)(d0 + dl) * NKBP + f - 1] : 0.0f;
  }
  __syncthreads();

  f32x4 acc[4][4];
  #pragma unroll
  for (int mi = 0; mi < 4; ++mi)
    #pragma unroll
    for (int ni = 0; ni < 4; ++ni) acc[mi][ni] = (f32x4){0.f, 0.f, 0.f, 0.f};

  const bool lg0 = (lg == 0);
  const unsigned short* bptr[4];
  #pragma unroll
  for (int ni = 0; ni < 4; ++ni)
    bptr[ni] = w2u + (size_t)(bN + ni * 16 + lr) * NKP + (size_t)d0 * 64 + lg * 8;
  const float* xrow[4];
  #pragma unroll
  for (int mi = 0; mi < 4; ++mi)
    xrow[mi] = x + (size_t)(bM + w * 64 + mi * 16 + lr) * ND + d0;

  for (int c = 0; c < 8; ++c) {
    f32x4 xqa[4], xqb[4];
    #pragma unroll
    for (int mi = 0; mi < 4; ++mi) {
      xqa[mi] = *(const f32x4*)(xrow[mi] + c * 8);
      xqb[mi] = *(const f32x4*)(xrow[mi] + c * 8 + 4);
    }
    #pragma unroll
    for (int dd = 0; dd < 8; ++dd) {
      const int dl = c * 8 + dd;
      short8_t bfr[2][4];
      #pragma unroll
      for (int kf = 0; kf < 2; ++kf)
        #pragma unroll
        for (int ni = 0; ni < 4; ++ni)
          bfr[kf][ni] = *(const short8_t*)(bptr[ni] + dl * 64 + kf * 32);
      const float* tp = thrS + dl * 64 + lg * 8;
      f32x4 ta = *(const f32x4*)(tp);
      f32x4 tb = *(const f32x4*)(tp + 4);
      f32x4 tc = *(const f32x4*)(tp + 32);
      f32x4 td = *(const f32x4*)(tp + 36);
      short8_t afr[4][2];
      #pragma unroll
      for (int mi = 0; mi < 4; ++mi) {
        const float xv = (dd < 4) ? xqa[mi][dd & 3] : xqb[mi][dd & 3];
        short8_t A0, A1;
        A0[0] = (short)bfbits(lg0 ? xv : fmaxf(xv - ta[0], 0.f));
        A0[1] = (short)bfbits(fmaxf(xv - ta[1], 0.f));
        A0[2] = (short)bfbits(fmaxf(xv - ta[2], 0.f));
        A0[3] = (short)bfbits(fmaxf(xv - ta[3], 0.f));
        A0[4] = (short)bfbits(fmaxf(xv - tb[0], 0.f));
        A0[5] = (short)bfbits(fmaxf(xv - tb[1], 0.f));
        A0[6] = (short)bfbits(fmaxf(xv - tb[2], 0.f));
        A0[7] = (short)bfbits(fmaxf(xv - tb[3], 0.f));
        A1[0] = (short)bfbits(fmaxf(xv - tc[0], 0.f));
        A1[1] = (short)bfbits(fmaxf(xv - tc[1], 0.f));
        A1[2] = (short)bfbits(fmaxf(xv - tc[2], 0.f));
        A1[3] = (short)bfbits(fmaxf(xv - tc[3], 0.f));
        A1[4] = (short)bfbits(fmaxf(xv - td[0], 0.f));
        A1[5] = (short)bfbits(fmaxf(xv - td[1], 0.f));
        A1[6] = (short)bfbits(fmaxf(xv - td[2], 0.f));
        A1[7] = (short)bfbits(fmaxf(xv - td[3], 0.f));
        afr[mi][0] = A0;
        afr[mi][1] = A1;
      }
      #pragma unroll
      for (int kf = 0; kf < 2; ++kf)
        #pragma unroll
        for (int mi = 0; mi < 4; ++mi)
          #pragma unroll
          for (int ni = 0; ni < 4; ++ni)
            acc[mi][ni] = __builtin_amdgcn_mfma_f32_16x16x32_bf16(afr[mi][kf], bfr[kf][ni], acc[mi][ni], 0, 0, 0);
    }
  }

  float* pp = pbuf + (size_t)blockIdx.z * ((size_t)NB * ND);
  #pragma unroll
  for (int mi = 0; mi < 4; ++mi)
    #pragma unroll
    for (int ni = 0; ni < 4; ++ni) {
      const int col = bN + ni * 16 + lr;
      const int rowb = bM + w * 64 + mi * 16 + lg * 4;
      #pragma unroll
      for (int r = 0; r < 4; ++r)
        pp[(size_t)(rowb + r) * ND + col] = acc[mi][ni][r];
    }
}

// ---------------- K4: combine partials -> x_emb ----------------
__global__ void k_comb(const float* __restrict__ x, const float* __restrict__ pbuf,
                       const float* __restrict__ cbuf, const float* __restrict__ pb,
                       float* __restrict__ xe) {
  const size_t i = ((size_t)blockIdx.x * 256 + threadIdx.x) * 4;
  const int n = (int)(i & 255);
  f32x4 s = *(const f32x4*)(pbuf + i);
  s += *(const f32x4*)(pbuf + (size_t)1 * 2097152 + i);
  s += *(const f32x4*)(pbuf + (size_t)2 * 2097152 + i);
  s += *(const f32x4*)(pbuf + (size_t)3 * 2097152 + i);
  f32x4 cv = *(const f32x4*)(cbuf + n);
  f32x4 pv = *(const f32x4*)(pb + n);
  f32x4 xv = *(const f32x4*)(x + i);
  *(f32x4*)(xe + i) = xv + 0.1f * (s + cv + pv);
}

// ---------------- K5: embeddings via bf16 MFMA (write-BW-bound) ----------------
__global__ __launch_bounds__(256, 2) void k_emb(
    const float* __restrict__ x, const float* __restrict__ bw,
    const float* __restrict__ bb, const float* __restrict__ bp,
    float* __restrict__ oe) {
  const int d = blockIdx.y;
  const int b0 = blockIdx.x * 256;
  const int t = threadIdx.x;
  const int l = t & 63, w = t >> 6;
  const int lr = l & 15, lg = l >> 4;
  __shared__ unsigned short btS[64 * 72];  // [e][f] bf16 (transposed bw[d]), rows padded
  __shared__ float thrF[64];
  __shared__ float bbS[64];
  if (t < 64) thrF[t] = (t >= 1) ? bp[(size_t)d * NKBP + t - 1] : 0.0f;
  else if (t < 128) bbS[t - 64] = bb[(size_t)d * 64 + (t - 64)];
  {
    const float* bwd = bw + (size_t)d * 4096;
    const int f = t >> 2, e0 = (t & 3) * 16;
    #pragma unroll
    for (int q = 0; q < 4; ++q) {
      f32x4 v = *(const f32x4*)(bwd + f * 64 + e0 + q * 4);
      #pragma unroll
      for (int r = 0; r < 4; ++r) {
        const int e = e0 + q * 4 + r;
        btS[e * 72 + f] = bfbits(v[r]);
      }
    }
  }
  __syncthreads();

  f32x4 ta = *(const f32x4*)(thrF + lg * 8);
  f32x4 tb = *(const f32x4*)(thrF + lg * 8 + 4);
  f32x4 tc = *(const f32x4*)(thrF + 32 + lg * 8);
  f32x4 td = *(const f32x4*)(thrF + 36 + lg * 8);
  const bool lg0 = (lg == 0);

  short8_t afr[4][2];
  #pragma unroll
  for (int mi = 0; mi < 4; ++mi) {
    const float xv = x[(size_t)(b0 + w * 64 + mi * 16 + lr) * ND + d];
    short8_t A0, A1;
    A0[0] = (short)bfbits(lg0 ? xv : fmaxf(xv - ta[0], 0.f));
    A0[1] = (short)bfbits(fmaxf(xv - ta[1], 0.f));
    A0[2] = (short)bfbits(fmaxf(xv - ta[2], 0.f));
    A0[3] = (short)bfbits(fmaxf(xv - ta[3], 0.f));
    A0[4] = (short)bfbits(fmaxf(xv - tb[0], 0.f));
    A0[5] = (short)bfbits(fmaxf(xv - tb[1], 0.f));
    A0[6] = (short)bfbits(fmaxf(xv - tb[2], 0.f));
    A0[7] = (short)bfbits(fmaxf(xv - tb[3], 0.f));
    A1[0] = (short)bfbits(fmaxf(xv - tc[0], 0.f));
    A1[1] = (short)bfbits(fmaxf(xv - tc[1], 0.f));
    A1[2] = (short)bfbits(fmaxf(xv - tc[2], 0.f));
    A1[3] = (short)bfbits(fmaxf(xv - tc[3], 0.f));
    A1[4] = (short)bfbits(fmaxf(xv - td[0], 0.f));
    A1[5] = (short)bfbits(fmaxf(xv - td[1], 0.f));
    A1[6] = (short)bfbits(fmaxf(xv - td[2], 0.f));
    A1[7] = (short)bfbits(fmaxf(xv - td[3], 0.f));
    afr[mi][0] = A0;
    afr[mi][1] = A1;
  }
  short8_t bfr[4][2];
  #pragma unroll
  for (int ni = 0; ni < 4; ++ni) {
    const int e = ni * 16 + lr;
    #pragma unroll
    for (int kf = 0; kf < 2; ++kf)
      bfr[ni][kf] = *(const short8_t*)(btS + e * 72 + kf * 32 + lg * 8);
  }
  f32x4 acc[4][4];
  #pragma unroll
  for (int mi = 0; mi < 4; ++mi)
    #pragma unroll
    for (int ni = 0; ni < 4; ++ni) acc[mi][ni] = (f32x4){0.f, 0.f, 0.f, 0.f};
  #pragma unroll
  for (int kf = 0; kf < 2; ++kf)
    #pragma unroll
    for (int mi = 0; mi < 4; ++mi)
      #pragma unroll
      for (int ni = 0; ni < 4; ++ni)
        acc[mi][ni] = __builtin_amdgcn_mfma_f32_16x16x32_bf16(afr[mi][kf], bfr[ni][kf], acc[mi][ni], 0, 0, 0);

  #pragma unroll
  for (int ni = 0; ni < 4; ++ni) {
    const float bbv = bbS[ni * 16 + lr];
    const int col = d * 64 + ni * 16 + lr;
    #pragma unroll
    for (int mi = 0; mi < 4; ++mi) {
      const int rowb = b0 + w * 64 + mi * 16 + lg * 4;
      #pragma unroll
      for (int r = 0; r < 4; ++r)
        oe[(size_t)(rowb + r) * NDE + col] = acc[mi][ni][r] + bbv;
    }
  }
}

extern "C" void kernel_launch(void* const* d_in, const int* in_sizes, int n_in,
                              void* d_out, int out_size, void* d_ws, size_t ws_size,
                              hipStream_t stream) {
  const float* x    = (const float*)d_in[0];
  const float* bw   = (const float*)d_in[1];
  const float* bb   = (const float*)d_in[2];
  const float* pw   = (const float*)d_in[3];
  const float* pb   = (const float*)d_in[4];
  const float* bmin = (const float*)d_in[5];
  const float* draw = (const float*)d_in[6];

  float* out    = (float*)d_out;
  float* out_x  = out;                          // [8192*256]
  float* out_e  = out + (size_t)NB * ND;        // [8192*256*64]
  float* out_bp = out_e + (size_t)NB * NDE;     // [256*63]

  // Scratch: w2t fills out_x region EXACTLY (2M f32 = 4.2M bf16); overwritten by k_comb after k_proj.
  unsigned short* w2t = (unsigned short*)out_x;
  // cbuf + split-K partials + cb_part at head of out_e; consumed by k_comb, then overwritten by k_emb.
  float* cbuf    = out_e;                       // 256 f32
  float* pbuf    = out_e + 65536;               // 4 * 2097152 f32 = 33.5 MB
  float* cb_part = out_e + 65536 + 4 * 2097152; // 256*256 f32 = 256 KB

  k_bp  <<<dim3(1),          dim3(256), 0, stream>>>(bmin, draw, out_bp);
  k_w2  <<<dim3(256),        dim3(256), 0, stream>>>(bw, pw, bb, w2t, cb_part);
  k_cbr <<<dim3(1),          dim3(256), 0, stream>>>(cb_part, cbuf);
  k_proj<<<dim3(32, 4, 4),   dim3(256), 0, stream>>>(w2t, out_bp, x, pbuf);
  k_comb<<<dim3(2048),       dim3(256), 0, stream>>>(x, pbuf, cbuf, pb, out_x);
  k_emb <<<dim3(32, 256),    dim3(256), 0, stream>>>(x, bw, bb, out_bp, out_e);
}

// Round 5
// 297.816 us; speedup vs baseline: 2.6692x; 1.0661x over previous
//
#include <hip/hip_runtime.h>
#include <hip/hip_bf16.h>

#define NB 8192
#define ND 256
#define NKBP 63
#define NF 64
#define NE 64
#define NKP 16384   // D*F
#define NDE 16384   // D*E

typedef __attribute__((ext_vector_type(8))) short short8_t;
typedef __attribute__((ext_vector_type(4))) short short4_t;
typedef __attribute__((ext_vector_type(4))) float f32x4;

__device__ __forceinline__ unsigned short bfbits(float v) {
  union { __hip_bfloat16 b; unsigned short u; } cv;
  cv.b = __float2bfloat16(v);
  return cv.u;
}
__device__ __forceinline__ float bf2f(unsigned short s) {
  return __uint_as_float(((unsigned)s) << 16);
}

// ---------------- K1: breakpoints = bmin + cumsum(softplus(draw)) ----------------
__global__ void k_bp(const float* __restrict__ bmin, const float* __restrict__ draw,
                     float* __restrict__ obp) {
  const int d = blockIdx.x * blockDim.x + threadIdx.x;
  if (d >= ND) return;
  float a = bmin[d];
  for (int j = 0; j < NKBP; ++j) {
    float r = draw[d * NKBP + j];
    a += fmaxf(r, 0.f) + log1pf(expf(-fabsf(r)));
    obp[d * NKBP + j] = a;
  }
}

// ---------------- K2: W2 (fragment-native blocked layout) + cbias partials ----------------
// Logical W2[n][k], k=d*64+f. Stored: w2f[(((d*2+kf)*4+lg)*256 + n)*8 + j],
// where f = kf*32 + lg*8 + j. This makes k_proj's B-frag loads coalesced.
__global__ __launch_bounds__(256, 2) void k_w2(
    const float* __restrict__ bw, const float* __restrict__ pw,
    const float* __restrict__ bb, unsigned short* __restrict__ w2f,
    float* __restrict__ cb_part) {
  const int d = blockIdx.x;
  const int t = threadIdx.x;
  const int l = t & 63, w = t >> 6;
  const int lr = l & 15, lg = l >> 4;
  __shared__ unsigned short pwS[256 * 72];  // [n][e] bf16, rows padded to 72
  __shared__ unsigned short bwS[64 * 72];   // [f][e] bf16
  __shared__ float bbS[64];

  {  // stage pw slice [256 n][64 e] -> bf16 LDS, coalesced (16 lanes per row)
    const int rr = t >> 4, e0 = (t & 15) * 4;
    #pragma unroll
    for (int it = 0; it < 16; ++it) {
      const int n = it * 16 + rr;
      f32x4 v = *(const f32x4*)(pw + (size_t)n * NDE + d * 64 + e0);
      short4_t s;
      s[0] = (short)bfbits(v[0]); s[1] = (short)bfbits(v[1]);
      s[2] = (short)bfbits(v[2]); s[3] = (short)bfbits(v[3]);
      *(short4_t*)(pwS + n * 72 + e0) = s;
    }
    #pragma unroll
    for (int it = 0; it < 4; ++it) {
      const int f = it * 16 + rr;
      f32x4 v = *(const f32x4*)(bw + (size_t)d * 4096 + f * 64 + e0);
      short4_t s;
      s[0] = (short)bfbits(v[0]); s[1] = (short)bfbits(v[1]);
      s[2] = (short)bfbits(v[2]); s[3] = (short)bfbits(v[3]);
      *(short4_t*)(bwS + f * 72 + e0) = s;
    }
    if (t < 64) bbS[t] = bb[(size_t)d * 64 + t];
  }
  __syncthreads();

  f32x4 acc[4][4];
  #pragma unroll
  for (int mi = 0; mi < 4; ++mi)
    #pragma unroll
    for (int ni = 0; ni < 4; ++ni) acc[mi][ni] = (f32x4){0.f, 0.f, 0.f, 0.f};

  short8_t afr[4][2], bfr[4][2];
  #pragma unroll
  for (int kf = 0; kf < 2; ++kf) {
    #pragma unroll
    for (int mi = 0; mi < 4; ++mi) {
      const int n = w * 64 + mi * 16 + lr;
      afr[mi][kf] = *(const short8_t*)(pwS + n * 72 + kf * 32 + lg * 8);
    }
    #pragma unroll
    for (int ni = 0; ni < 4; ++ni) {
      const int f = ni * 16 + lr;
      bfr[ni][kf] = *(const short8_t*)(bwS + f * 72 + kf * 32 + lg * 8);
    }
  }
  #pragma unroll
  for (int kf = 0; kf < 2; ++kf)
    #pragma unroll
    for (int mi = 0; mi < 4; ++mi)
      #pragma unroll
      for (int ni = 0; ni < 4; ++ni)
        acc[mi][ni] = __builtin_amdgcn_mfma_f32_16x16x32_bf16(afr[mi][kf], bfr[ni][kf], acc[mi][ni], 0, 0, 0);

  // store into fragment-native layout: element (n = nb+r, f = ni*16+lr)
  #pragma unroll
  for (int mi = 0; mi < 4; ++mi)
    #pragma unroll
    for (int ni = 0; ni < 4; ++ni) {
      const int kf_s = ni >> 1;
      const int lgp  = (ni * 2 + (lr >> 3)) & 3;
      const int jj   = lr & 7;
      const int nb   = w * 64 + mi * 16 + lg * 4;
      const size_t base = (((size_t)d * 2 + kf_s) * 4 + lgp) * 256;
      #pragma unroll
      for (int r = 0; r < 4; ++r)
        w2f[(base + (nb + r)) * 8 + jj] = bfbits(acc[mi][ni][r]);
    }

  // cbias partial for this d: thread t owns n = t
  {
    float cacc = 0.f;
    #pragma unroll 8
    for (int e = 0; e < 64; ++e) cacc += bf2f(pwS[t * 72 + e]) * bbS[e];
    cb_part[(size_t)d * 256 + t] = cacc;
  }
}

// ---------------- K2r: cbias[n] = sum_d cb_part[d][n] ----------------
__global__ void k_cbr(const float* __restrict__ cb_part, float* __restrict__ c) {
  const int t = threadIdx.x;
  float acc = 0.f;
  for (int d = 0; d < ND; ++d) acc += cb_part[(size_t)d * 256 + t];
  c[t] = acc;
}

// ---------------- K3: projection GEMM partials. Split-K x4, no barriers in K-loop.
// wave-tile 64x64 (mi=4, ni=4), A (basis) in registers, B coalesced from w2f.
__global__ __launch_bounds__(256, 2) void k_proj(
    const unsigned short* __restrict__ w2f, const float* __restrict__ bp,
    const float* __restrict__ x, float* __restrict__ pbuf) {
  const int t = threadIdx.x;
  const int l = t & 63, w = t >> 6;
  const int lr = l & 15, lg = l >> 4;
  const int bM = blockIdx.x * 256;
  const int bN = blockIdx.y * 64;
  const int d0 = blockIdx.z * 64;
  __shared__ float thrS[64 * 64];   // thrS[dl*64+f] = (f==0)?0:bp[d0+dl][f-1]

  for (int i = t; i < 4096; i += 256) {
    const int dl = i >> 6, f = i & 63;
    thrS[i] = (f >= 1) ? bp[(size_t)(d0 + dl) * NKBP + f - 1] : 0.0f;
  }
  __syncthreads();

  f32x4 acc[4][4];
  #pragma unroll
  for (int mi = 0; mi < 4; ++mi)
    #pragma unroll
    for (int ni = 0; ni < 4; ++ni) acc[mi][ni] = (f32x4){0.f, 0.f, 0.f, 0.f};

  const bool lg0 = (lg == 0);
  // elem addr = d*16384 + kf*8192 + lg*2048 + n*8 + j
  const unsigned short* bbase[4];
  #pragma unroll
  for (int ni = 0; ni < 4; ++ni)
    bbase[ni] = w2f + (size_t)d0 * 16384 + (size_t)(bN + ni * 16 + lr) * 8 + (size_t)lg * 2048;
  const float* xrow[4];
  #pragma unroll
  for (int mi = 0; mi < 4; ++mi)
    xrow[mi] = x + (size_t)(bM + w * 64 + mi * 16 + lr) * ND + d0;

  for (int c = 0; c < 8; ++c) {
    f32x4 xqa[4], xqb[4];
    #pragma unroll
    for (int mi = 0; mi < 4; ++mi) {
      xqa[mi] = *(const f32x4*)(xrow[mi] + c * 8);
      xqb[mi] = *(const f32x4*)(xrow[mi] + c * 8 + 4);
    }
    #pragma unroll
    for (int dd = 0; dd < 8; ++dd) {
      const int dl = c * 8 + dd;
      short8_t bfr[2][4];
      #pragma unroll
      for (int kf = 0; kf < 2; ++kf)
        #pragma unroll
        for (int ni = 0; ni < 4; ++ni)
          bfr[kf][ni] = *(const short8_t*)(bbase[ni] + (size_t)dl * 16384 + kf * 8192);
      const float* tp = thrS + dl * 64 + lg * 8;
      f32x4 ta = *(const f32x4*)(tp);
      f32x4 tb = *(const f32x4*)(tp + 4);
      f32x4 tc = *(const f32x4*)(tp + 32);
      f32x4 td = *(const f32x4*)(tp + 36);
      short8_t afr[4][2];
      #pragma unroll
      for (int mi = 0; mi < 4; ++mi) {
        const float xv = (dd < 4) ? xqa[mi][dd & 3] : xqb[mi][dd & 3];
        short8_t A0, A1;
        A0[0] = (short)bfbits(lg0 ? xv : fmaxf(xv - ta[0], 0.f));
        A0[1] = (short)bfbits(fmaxf(xv - ta[1], 0.f));
        A0[2] = (short)bfbits(fmaxf(xv - ta[2], 0.f));
        A0[3] = (short)bfbits(fmaxf(xv - ta[3], 0.f));
        A0[4] = (short)bfbits(fmaxf(xv - tb[0], 0.f));
        A0[5] = (short)bfbits(fmaxf(xv - tb[1], 0.f));
        A0[6] = (short)bfbits(fmaxf(xv - tb[2], 0.f));
        A0[7] = (short)bfbits(fmaxf(xv - tb[3], 0.f));
        A1[0] = (short)bfbits(fmaxf(xv - tc[0], 0.f));
        A1[1] = (short)bfbits(fmaxf(xv - tc[1], 0.f));
        A1[2] = (short)bfbits(fmaxf(xv - tc[2], 0.f));
        A1[3] = (short)bfbits(fmaxf(xv - tc[3], 0.f));
        A1[4] = (short)bfbits(fmaxf(xv - td[0], 0.f));
        A1[5] = (short)bfbits(fmaxf(xv - td[1], 0.f));
        A1[6] = (short)bfbits(fmaxf(xv - td[2], 0.f));
        A1[7] = (short)bfbits(fmaxf(xv - td[3], 0.f));
        afr[mi][0] = A0;
        afr[mi][1] = A1;
      }
      #pragma unroll
      for (int kf = 0; kf < 2; ++kf)
        #pragma unroll
        for (int mi = 0; mi < 4; ++mi)
          #pragma unroll
          for (int ni = 0; ni < 4; ++ni)
            acc[mi][ni] = __builtin_amdgcn_mfma_f32_16x16x32_bf16(afr[mi][kf], bfr[kf][ni], acc[mi][ni], 0, 0, 0);
    }
  }

  float* pp = pbuf + (size_t)blockIdx.z * ((size_t)NB * ND);
  #pragma unroll
  for (int mi = 0; mi < 4; ++mi)
    #pragma unroll
    for (int ni = 0; ni < 4; ++ni) {
      const int col = bN + ni * 16 + lr;
      const int rowb = bM + w * 64 + mi * 16 + lg * 4;
      #pragma unroll
      for (int r = 0; r < 4; ++r)
        pp[(size_t)(rowb + r) * ND + col] = acc[mi][ni][r];
    }
}

// ---------------- K4: combine partials -> x_emb ----------------
__global__ void k_comb(const float* __restrict__ x, const float* __restrict__ pbuf,
                       const float* __restrict__ cbuf, const float* __restrict__ pb,
                       float* __restrict__ xe) {
  const size_t i = ((size_t)blockIdx.x * 256 + threadIdx.x) * 4;
  const int n = (int)(i & 255);
  f32x4 s = *(const f32x4*)(pbuf + i);
  s += *(const f32x4*)(pbuf + (size_t)1 * 2097152 + i);
  s += *(const f32x4*)(pbuf + (size_t)2 * 2097152 + i);
  s += *(const f32x4*)(pbuf + (size_t)3 * 2097152 + i);
  f32x4 cv = *(const f32x4*)(cbuf + n);
  f32x4 pv = *(const f32x4*)(pb + n);
  f32x4 xv = *(const f32x4*)(x + i);
  *(f32x4*)(xe + i) = xv + 0.1f * (s + cv + pv);
}

// ---------------- K5: embeddings via bf16 MFMA (write-BW-bound) ----------------
__global__ __launch_bounds__(256, 2) void k_emb(
    const float* __restrict__ x, const float* __restrict__ bw,
    const float* __restrict__ bb, const float* __restrict__ bp,
    float* __restrict__ oe) {
  const int d = blockIdx.y;
  const int b0 = blockIdx.x * 256;
  const int t = threadIdx.x;
  const int l = t & 63, w = t >> 6;
  const int lr = l & 15, lg = l >> 4;
  __shared__ unsigned short btS[64 * 72];  // [e][f] bf16 (transposed bw[d]), rows padded
  __shared__ float thrF[64];
  __shared__ float bbS[64];
  if (t < 64) thrF[t] = (t >= 1) ? bp[(size_t)d * NKBP + t - 1] : 0.0f;
  else if (t < 128) bbS[t - 64] = bb[(size_t)d * 64 + (t - 64)];
  {
    const float* bwd = bw + (size_t)d * 4096;
    const int f = t >> 2, e0 = (t & 3) * 16;
    #pragma unroll
    for (int q = 0; q < 4; ++q) {
      f32x4 v = *(const f32x4*)(bwd + f * 64 + e0 + q * 4);
      #pragma unroll
      for (int r = 0; r < 4; ++r) {
        const int e = e0 + q * 4 + r;
        btS[e * 72 + f] = bfbits(v[r]);
      }
    }
  }
  __syncthreads();

  f32x4 ta = *(const f32x4*)(thrF + lg * 8);
  f32x4 tb = *(const f32x4*)(thrF + lg * 8 + 4);
  f32x4 tc = *(const f32x4*)(thrF + 32 + lg * 8);
  f32x4 td = *(const f32x4*)(thrF + 36 + lg * 8);
  const bool lg0 = (lg == 0);

  short8_t afr[4][2];
  #pragma unroll
  for (int mi = 0; mi < 4; ++mi) {
    const float xv = x[(size_t)(b0 + w * 64 + mi * 16 + lr) * ND + d];
    short8_t A0, A1;
    A0[0] = (short)bfbits(lg0 ? xv : fmaxf(xv - ta[0], 0.f));
    A0[1] = (short)bfbits(fmaxf(xv - ta[1], 0.f));
    A0[2] = (short)bfbits(fmaxf(xv - ta[2], 0.f));
    A0[3] = (short)bfbits(fmaxf(xv - ta[3], 0.f));
    A0[4] = (short)bfbits(fmaxf(xv - tb[0], 0.f));
    A0[5] = (short)bfbits(fmaxf(xv - tb[1], 0.f));
    A0[6] = (short)bfbits(fmaxf(xv - tb[2], 0.f));
    A0[7] = (short)bfbits(fmaxf(xv - tb[3], 0.f));
    A1[0] = (short)bfbits(fmaxf(xv - tc[0], 0.f));
    A1[1] = (short)bfbits(fmaxf(xv - tc[1], 0.f));
    A1[2] = (short)bfbits(fmaxf(xv - tc[2], 0.f));
    A1[3] = (short)bfbits(fmaxf(xv - tc[3], 0.f));
    A1[4] = (short)bfbits(fmaxf(xv - td[0], 0.f));
    A1[5] = (short)bfbits(fmaxf(xv - td[1], 0.f));
    A1[6] = (short)bfbits(fmaxf(xv - td[2], 0.f));
    A1[7] = (short)bfbits(fmaxf(xv - td[3], 0.f));
    afr[mi][0] = A0;
    afr[mi][1] = A1;
  }
  short8_t bfr[4][2];
  #pragma unroll
  for (int ni = 0; ni < 4; ++ni) {
    const int e = ni * 16 + lr;
    #pragma unroll
    for (int kf = 0; kf < 2; ++kf)
      bfr[ni][kf] = *(const short8_t*)(btS + e * 72 + kf * 32 + lg * 8);
  }
  f32x4 acc[4][4];
  #pragma unroll
  for (int mi = 0; mi < 4; ++mi)
    #pragma unroll
    for (int ni = 0; ni < 4; ++ni) acc[mi][ni] = (f32x4){0.f, 0.f, 0.f, 0.f};
  #pragma unroll
  for (int kf = 0; kf < 2; ++kf)
    #pragma unroll
    for (int mi = 0; mi < 4; ++mi)
      #pragma unroll
      for (int ni = 0; ni < 4; ++ni)
        acc[mi][ni] = __builtin_amdgcn_mfma_f32_16x16x32_bf16(afr[mi][kf], bfr[ni][kf], acc[mi][ni], 0, 0, 0);

  #pragma unroll
  for (int ni = 0; ni < 4; ++ni) {
    const float bbv = bbS[ni * 16 + lr];
    const int col = d * 64 + ni * 16 + lr;
    #pragma unroll
    for (int mi = 0; mi < 4; ++mi) {
      const int rowb = b0 + w * 64 + mi * 16 + lg * 4;
      #pragma unroll
      for (int r = 0; r < 4; ++r)
        oe[(size_t)(rowb + r) * NDE + col] = acc[mi][ni][r] + bbv;
    }
  }
}

extern "C" void kernel_launch(void* const* d_in, const int* in_sizes, int n_in,
                              void* d_out, int out_size, void* d_ws, size_t ws_size,
                              hipStream_t stream) {
  const float* x    = (const float*)d_in[0];
  const float* bw   = (const float*)d_in[1];
  const float* bb   = (const float*)d_in[2];
  const float* pw   = (const float*)d_in[3];
  const float* pb   = (const float*)d_in[4];
  const float* bmin = (const float*)d_in[5];
  const float* draw = (const float*)d_in[6];

  float* out    = (float*)d_out;
  float* out_x  = out;                          // [8192*256]
  float* out_e  = out + (size_t)NB * ND;        // [8192*256*64]
  float* out_bp = out_e + (size_t)NB * NDE;     // [256*63]

  // Scratch: w2f fills out_x region EXACTLY (2M f32 = 4.2M bf16); overwritten by k_comb after k_proj.
  unsigned short* w2f = (unsigned short*)out_x;
  // cbuf + split-K partials + cb_part at head of out_e; consumed by k_comb, then overwritten by k_emb.
  float* cbuf    = out_e;                       // 256 f32
  float* pbuf    = out_e + 65536;               // 4 * 2097152 f32 = 33.5 MB
  float* cb_part = out_e + 65536 + 4 * 2097152; // 256*256 f32 = 256 KB

  k_bp  <<<dim3(1),          dim3(256), 0, stream>>>(bmin, draw, out_bp);
  k_w2  <<<dim3(256),        dim3(256), 0, stream>>>(bw, pw, bb, w2f, cb_part);
  k_cbr <<<dim3(1),          dim3(256), 0, stream>>>(cb_part, cbuf);
  k_proj<<<dim3(32, 4, 4),   dim3(256), 0, stream>>>(w2f, out_bp, x, pbuf);
  k_comb<<<dim3(2048),       dim3(256), 0, stream>>>(x, pbuf, cbuf, pb, out_x);
  k_emb <<<dim3(32, 256),    dim3(256), 0, stream>>>(x, bw, bb, out_bp, out_e);
}